// Round 6
// baseline (615.348 us; speedup 1.0000x reference)
//
#include <hip/hip_runtime.h>
#include <math.h>

#define B_   64
#define C_   768
#define HW_  1024          // 32*32
#define NCLS 100
#define E_   16
#define K_   2
#define FAN  (C_ + NCLS)   // 868
#define POOL_BLOCKS 6144   // 49152 rows / (4 waves * 2 rows)
#define ROWS_PER_BATCH 768

typedef float vfloat4 __attribute__((ext_vector_type(4)));

// Fused: blocks [0,6144) pool; blocks [6144,6208) are per-batch routers that
// spin on agent-scope row counters (message passing, no __threadfence).
__global__ __launch_bounds__(256) void fused_kernel(const float* __restrict__ x,
                                                    const float* __restrict__ task_cls,
                                                    const float* __restrict__ Wm,
                                                    const float* __restrict__ bias,
                                                    float* __restrict__ out,
                                                    float* __restrict__ pooled,
                                                    unsigned int* __restrict__ counters) {
    const int tid  = threadIdx.x;
    const int lane = tid & 63;
    const int wav  = tid >> 6;

    if (blockIdx.x < POOL_BLOCKS) {
        // ---------- pool: one wave per TWO rows of 1024 contiguous floats ----------
        const int wave = (blockIdx.x * 256 + tid) >> 6;   // 0..24575
        const int r0   = wave * 2;
        const vfloat4* p0 = reinterpret_cast<const vfloat4*>(x + (size_t)r0 * HW_);
        const vfloat4* p1 = reinterpret_cast<const vfloat4*>(x + (size_t)(r0 + 1) * HW_);
        vfloat4 a0 = p0[lane];
        vfloat4 a1 = p0[lane + 64];
        vfloat4 a2 = p0[lane + 128];
        vfloat4 a3 = p0[lane + 192];
        vfloat4 b0 = p1[lane];
        vfloat4 b1 = p1[lane + 64];
        vfloat4 b2 = p1[lane + 128];
        vfloat4 b3 = p1[lane + 192];

        float s0 = (a0.x + a0.y + a0.z + a0.w) + (a1.x + a1.y + a1.z + a1.w)
                 + (a2.x + a2.y + a2.z + a2.w) + (a3.x + a3.y + a3.z + a3.w);
        float s1 = (b0.x + b0.y + b0.z + b0.w) + (b1.x + b1.y + b1.z + b1.w)
                 + (b2.x + b2.y + b2.z + b2.w) + (b3.x + b3.y + b3.z + b3.w);

        #pragma unroll
        for (int off = 32; off > 0; off >>= 1) {
            s0 += __shfl_down(s0, off);
            s1 += __shfl_down(s1, off);
        }
        if (lane == 0) {
            // agent-scope stores go to the coherent point; no fence needed
            __hip_atomic_store(&pooled[r0],     s0 * (1.0f / 1024.0f),
                               __ATOMIC_RELAXED, __HIP_MEMORY_SCOPE_AGENT);
            __hip_atomic_store(&pooled[r0 + 1], s1 * (1.0f / 1024.0f),
                               __ATOMIC_RELAXED, __HIP_MEMORY_SCOPE_AGENT);
            const int b = r0 / ROWS_PER_BATCH;   // both rows in same batch (r0 even)
            __hip_atomic_fetch_add(&counters[b], 2u,
                                   __ATOMIC_RELEASE, __HIP_MEMORY_SCOPE_AGENT);
        }
        return;
    }

    // ---------- router for batch b ----------
    const int b = blockIdx.x - POOL_BLOCKS;

    __shared__ float fused[FAN];
    __shared__ float logits_s[E_];
    __shared__ int   sel_s[K_];

    // task softmax first — independent of pooled, hides under the spin-wait
    if (tid < 64) {
        float v1 = task_cls[b * NCLS + tid];
        bool has2 = (tid + 64) < NCLS;
        float v2 = has2 ? task_cls[b * NCLS + tid + 64] : -INFINITY;
        float m = fmaxf(v1, v2);
        #pragma unroll
        for (int off = 32; off > 0; off >>= 1) m = fmaxf(m, __shfl_down(m, off));
        m = __shfl(m, 0);
        float e1 = __expf(v1 - m);
        float e2 = has2 ? __expf(v2 - m) : 0.0f;
        float sm = e1 + e2;
        #pragma unroll
        for (int off = 32; off > 0; off >>= 1) sm += __shfl_down(sm, off);
        sm = __shfl(sm, 0);
        float inv = 1.0f / sm;
        fused[C_ + tid] = e1 * inv;
        if (has2) fused[C_ + tid + 64] = e2 * inv;
    }

    // wait for this batch's 768 pooled rows
    if (tid == 0) {
        while (__hip_atomic_load(&counters[b], __ATOMIC_ACQUIRE,
                                 __HIP_MEMORY_SCOPE_AGENT) < (unsigned)ROWS_PER_BATCH)
            __builtin_amdgcn_s_sleep(1);
    }
    __syncthreads();

    for (int i = tid; i < C_; i += 256)
        fused[i] = __hip_atomic_load(&pooled[b * C_ + i],
                                     __ATOMIC_RELAXED, __HIP_MEMORY_SCOPE_AGENT);
    __syncthreads();

    // 16 expert dot products: wave w handles experts 4w..4w+3
    #pragma unroll
    for (int q = 0; q < 4; ++q) {
        const int e = wav * 4 + q;
        const float* wr = Wm + (size_t)e * FAN;
        float acc = 0.0f;
        for (int j = lane; j < FAN; j += 64) acc += fused[j] * wr[j];
        #pragma unroll
        for (int off = 32; off > 0; off >>= 1) acc += __shfl_down(acc, off);
        if (lane == 0) {
            float lg = acc + bias[e];
            logits_s[e] = lg;
            out[b * E_ + e] = lg;                 // router_logits [B,E] @ 0
        }
    }
    __syncthreads();

    // top-2 (strict > keeps lowest index on ties, matching lax.top_k)
    if (tid == 0) {
        float m1 = -INFINITY, m2 = -INFINITY;
        int i1 = 0, i2 = 0;
        #pragma unroll
        for (int e = 0; e < E_; ++e) {
            float v = logits_s[e];
            if (v > m1) { m2 = m1; i2 = i1; m1 = v; i1 = e; }
            else if (v > m2) { m2 = v; i2 = e; }
        }
        float r = expf(m2 - m1);
        float w0 = 1.0f / (1.0f + r);
        float w1 = r * w0;
        out[1024 + b * K_ + 0] = w0;              // router_weights [B,K] @ 1024
        out[1024 + b * K_ + 1] = w1;
        out[1152 + b * K_ + 0] = (float)i1;       // selected_experts [B,K] @ 1152
        out[1152 + b * K_ + 1] = (float)i2;
        sel_s[0] = i1; sel_s[1] = i2;
    }
    __syncthreads();

    // expert_mask [E,K,B] @ 1280 : flat e*K*B + k*B + b
    if (tid < E_ * K_) {
        int e = tid >> 1;
        int k = tid & 1;
        out[1280 + e * (K_ * B_) + k * B_ + b] = (sel_s[k] == e) ? 1.0f : 0.0f;
    }
}

extern "C" void kernel_launch(void* const* d_in, const int* in_sizes, int n_in,
                              void* d_out, int out_size, void* d_ws, size_t ws_size,
                              hipStream_t stream) {
    const float* hidden   = (const float*)d_in[0];  // [64,768,32,32]
    const float* task_cls = (const float*)d_in[1];  // [64,100]
    const float* Wm       = (const float*)d_in[2];  // [16,868]
    const float* bias     = (const float*)d_in[3];  // [16]
    float* out = (float*)d_out;

    unsigned int* counters = (unsigned int*)d_ws;      // 64 uints
    float* pooled = (float*)((char*)d_ws + 1024);      // B*C floats

    (void)hipMemsetAsync(counters, 0, B_ * sizeof(unsigned int), stream);
    fused_kernel<<<POOL_BLOCKS + B_, 256, 0, stream>>>(hidden, task_cls, Wm, bias,
                                                       out, pooled, counters);
}

// Round 7
// 216.678 us; speedup vs baseline: 2.8399x; 2.8399x over previous
//
#include <hip/hip_runtime.h>
#include <math.h>

#define B_   64
#define C_   768
#define HW_  1024          // 32*32
#define NCLS 100
#define E_   16
#define K_   2
#define FAN  (C_ + NCLS)   // 868
#define POOL_BLOCKS 6144   // 49152 rows / (4 waves * 2 rows)
#define ROWS_PER_BATCH 768

typedef float vfloat4 __attribute__((ext_vector_type(4)));

// Fused, fence-free: blocks [0,6144) pool; blocks [6144,6208) route.
// All cross-block traffic uses RELAXED agent-scope atomics (per-access cache
// bypass, no buffer_wbl2/buffer_inv). Producer ordering via s_waitcnt vmcnt(0).
__global__ __launch_bounds__(256) void fused_kernel(const float* __restrict__ x,
                                                    const float* __restrict__ task_cls,
                                                    const float* __restrict__ Wm,
                                                    const float* __restrict__ bias,
                                                    float* __restrict__ out,
                                                    float* __restrict__ pooled,
                                                    unsigned int* __restrict__ counters) {
    const int tid  = threadIdx.x;
    const int lane = tid & 63;
    const int wav  = tid >> 6;

    if (blockIdx.x < POOL_BLOCKS) {
        // ---------- pool: one wave per TWO rows of 1024 contiguous floats ----------
        const int wave = (blockIdx.x * 256 + tid) >> 6;   // 0..24575
        const int r0   = wave * 2;
        const vfloat4* p0 = reinterpret_cast<const vfloat4*>(x + (size_t)r0 * HW_);
        const vfloat4* p1 = reinterpret_cast<const vfloat4*>(x + (size_t)(r0 + 1) * HW_);
        vfloat4 a0 = p0[lane];
        vfloat4 a1 = p0[lane + 64];
        vfloat4 a2 = p0[lane + 128];
        vfloat4 a3 = p0[lane + 192];
        vfloat4 b0 = p1[lane];
        vfloat4 b1 = p1[lane + 64];
        vfloat4 b2 = p1[lane + 128];
        vfloat4 b3 = p1[lane + 192];

        float s0 = (a0.x + a0.y + a0.z + a0.w) + (a1.x + a1.y + a1.z + a1.w)
                 + (a2.x + a2.y + a2.z + a2.w) + (a3.x + a3.y + a3.z + a3.w);
        float s1 = (b0.x + b0.y + b0.z + b0.w) + (b1.x + b1.y + b1.z + b1.w)
                 + (b2.x + b2.y + b2.z + b2.w) + (b3.x + b3.y + b3.z + b3.w);

        #pragma unroll
        for (int off = 32; off > 0; off >>= 1) {
            s0 += __shfl_down(s0, off);
            s1 += __shfl_down(s1, off);
        }
        if (lane == 0) {
            __hip_atomic_store(&pooled[r0],     s0 * (1.0f / 1024.0f),
                               __ATOMIC_RELAXED, __HIP_MEMORY_SCOPE_AGENT);
            __hip_atomic_store(&pooled[r0 + 1], s1 * (1.0f / 1024.0f),
                               __ATOMIC_RELAXED, __HIP_MEMORY_SCOPE_AGENT);
            // ensure both data stores reached the coherence point, then bump
            asm volatile("s_waitcnt vmcnt(0)" ::: "memory");
            const int b = r0 / ROWS_PER_BATCH;
            __hip_atomic_fetch_add(&counters[b], 2u,
                                   __ATOMIC_RELAXED, __HIP_MEMORY_SCOPE_AGENT);
        }
        return;
    }

    // ---------- router for batch b ----------
    const int b = blockIdx.x - POOL_BLOCKS;

    __shared__ float fused[FAN];
    __shared__ float logits_s[E_];
    __shared__ int   sel_s[K_];

    // task softmax first — independent of pooled, hides under the wait
    if (tid < 64) {
        float v1 = task_cls[b * NCLS + tid];
        bool has2 = (tid + 64) < NCLS;
        float v2 = has2 ? task_cls[b * NCLS + tid + 64] : -INFINITY;
        float m = fmaxf(v1, v2);
        #pragma unroll
        for (int off = 32; off > 0; off >>= 1) m = fmaxf(m, __shfl_down(m, off));
        m = __shfl(m, 0);
        float e1 = __expf(v1 - m);
        float e2 = has2 ? __expf(v2 - m) : 0.0f;
        float sm = e1 + e2;
        #pragma unroll
        for (int off = 32; off > 0; off >>= 1) sm += __shfl_down(sm, off);
        sm = __shfl(sm, 0);
        float inv = 1.0f / sm;
        fused[C_ + tid] = e1 * inv;
        if (has2) fused[C_ + tid + 64] = e2 * inv;
    }

    // wait for this batch's 768 pooled rows (relaxed polls — no cache maintenance)
    if (tid == 0) {
        while (__hip_atomic_load(&counters[b], __ATOMIC_RELAXED,
                                 __HIP_MEMORY_SCOPE_AGENT) < (unsigned)ROWS_PER_BATCH)
            __builtin_amdgcn_s_sleep(2);
    }
    __syncthreads();

    for (int i = tid; i < C_; i += 256)
        fused[i] = __hip_atomic_load(&pooled[b * C_ + i],
                                     __ATOMIC_RELAXED, __HIP_MEMORY_SCOPE_AGENT);
    __syncthreads();

    // 16 expert dot products: wave w handles experts 4w..4w+3
    #pragma unroll
    for (int q = 0; q < 4; ++q) {
        const int e = wav * 4 + q;
        const float* wr = Wm + (size_t)e * FAN;
        float acc = 0.0f;
        for (int j = lane; j < FAN; j += 64) acc += fused[j] * wr[j];
        #pragma unroll
        for (int off = 32; off > 0; off >>= 1) acc += __shfl_down(acc, off);
        if (lane == 0) {
            float lg = acc + bias[e];
            logits_s[e] = lg;
            out[b * E_ + e] = lg;                 // router_logits [B,E] @ 0
        }
    }
    __syncthreads();

    // top-2 (strict > keeps lowest index on ties, matching lax.top_k)
    if (tid == 0) {
        float m1 = -INFINITY, m2 = -INFINITY;
        int i1 = 0, i2 = 0;
        #pragma unroll
        for (int e = 0; e < E_; ++e) {
            float v = logits_s[e];
            if (v > m1) { m2 = m1; i2 = i1; m1 = v; i1 = e; }
            else if (v > m2) { m2 = v; i2 = e; }
        }
        float r = expf(m2 - m1);
        float w0 = 1.0f / (1.0f + r);
        float w1 = r * w0;
        out[1024 + b * K_ + 0] = w0;              // router_weights [B,K] @ 1024
        out[1024 + b * K_ + 1] = w1;
        out[1152 + b * K_ + 0] = (float)i1;       // selected_experts [B,K] @ 1152
        out[1152 + b * K_ + 1] = (float)i2;
        sel_s[0] = i1; sel_s[1] = i2;
    }
    __syncthreads();

    // expert_mask [E,K,B] @ 1280 : flat e*K*B + k*B + b
    if (tid < E_ * K_) {
        int e = tid >> 1;
        int k = tid & 1;
        out[1280 + e * (K_ * B_) + k * B_ + b] = (sel_s[k] == e) ? 1.0f : 0.0f;
    }
}

extern "C" void kernel_launch(void* const* d_in, const int* in_sizes, int n_in,
                              void* d_out, int out_size, void* d_ws, size_t ws_size,
                              hipStream_t stream) {
    const float* hidden   = (const float*)d_in[0];  // [64,768,32,32]
    const float* task_cls = (const float*)d_in[1];  // [64,100]
    const float* Wm       = (const float*)d_in[2];  // [16,868]
    const float* bias     = (const float*)d_in[3];  // [16]
    float* out = (float*)d_out;

    unsigned int* counters = (unsigned int*)d_ws;      // 64 uints
    float* pooled = (float*)((char*)d_ws + 1024);      // B*C floats

    (void)hipMemsetAsync(counters, 0, B_ * sizeof(unsigned int), stream);
    fused_kernel<<<POOL_BLOCKS + B_, 256, 0, stream>>>(hidden, task_cls, Wm, bias,
                                                       out, pooled, counters);
}

// Round 8
// 55.310 us; speedup vs baseline: 11.1255x; 3.9176x over previous
//
#include <hip/hip_runtime.h>
#include <math.h>

#define B_   64
#define C_   768
#define HW_  1024          // 32*32
#define NCLS 100
#define E_   16
#define K_   2
#define FAN  (C_ + NCLS)   // 868
#define POOL_BLOCKS 6144   // 49152 rows / (4 waves * 2 rows)
#define BLOCKS_PER_BATCH 96
#define ROWS_PER_BATCH 768
#define CTR_STRIDE 16      // one counter per 64B line

typedef float vfloat4 __attribute__((ext_vector_type(4)));

// Fused, fence-free. Blocks [0,6144) pool; [6144,6208) route.
// Cross-block protocol: relaxed agent-scope atomics only (no buffer_wbl2 /
// buffer_inv). Producer: data stores -> s_waitcnt vmcnt(0) -> syncthreads ->
// ONE padded-counter RMW per block. Consumer: relaxed spin + relaxed reads.
__global__ __launch_bounds__(256) void fused_kernel(const float* __restrict__ x,
                                                    const float* __restrict__ task_cls,
                                                    const float* __restrict__ Wm,
                                                    const float* __restrict__ bias,
                                                    float* __restrict__ out,
                                                    float* __restrict__ pooled,
                                                    unsigned int* __restrict__ counters) {
    const int tid  = threadIdx.x;
    const int lane = tid & 63;
    const int wav  = tid >> 6;

    if (blockIdx.x < POOL_BLOCKS) {
        // ---------- pool: block = 8 rows (4 waves x 2 rows), all in one batch ----------
        const int r0 = blockIdx.x * 8 + wav * 2;
        const vfloat4* p0 = reinterpret_cast<const vfloat4*>(x + (size_t)r0 * HW_);
        const vfloat4* p1 = reinterpret_cast<const vfloat4*>(x + (size_t)(r0 + 1) * HW_);
        vfloat4 a0 = p0[lane];
        vfloat4 a1 = p0[lane + 64];
        vfloat4 a2 = p0[lane + 128];
        vfloat4 a3 = p0[lane + 192];
        vfloat4 b0 = p1[lane];
        vfloat4 b1 = p1[lane + 64];
        vfloat4 b2 = p1[lane + 128];
        vfloat4 b3 = p1[lane + 192];

        float s0 = (a0.x + a0.y + a0.z + a0.w) + (a1.x + a1.y + a1.z + a1.w)
                 + (a2.x + a2.y + a2.z + a2.w) + (a3.x + a3.y + a3.z + a3.w);
        float s1 = (b0.x + b0.y + b0.z + b0.w) + (b1.x + b1.y + b1.z + b1.w)
                 + (b2.x + b2.y + b2.z + b2.w) + (b3.x + b3.y + b3.z + b3.w);

        #pragma unroll
        for (int off = 32; off > 0; off >>= 1) {
            s0 += __shfl_down(s0, off);
            s1 += __shfl_down(s1, off);
        }
        if (lane == 0) {
            __hip_atomic_store(&pooled[r0],     s0 * (1.0f / 1024.0f),
                               __ATOMIC_RELAXED, __HIP_MEMORY_SCOPE_AGENT);
            __hip_atomic_store(&pooled[r0 + 1], s1 * (1.0f / 1024.0f),
                               __ATOMIC_RELAXED, __HIP_MEMORY_SCOPE_AGENT);
        }
        // scalar wait: this wave's stores have reached the coherence point
        asm volatile("s_waitcnt vmcnt(0)" ::: "memory");
        __syncthreads();                      // all 4 waves' stores are visible
        if (tid == 0) {
            const int b = blockIdx.x / BLOCKS_PER_BATCH;
            __hip_atomic_fetch_add(&counters[b * CTR_STRIDE], 8u,
                                   __ATOMIC_RELAXED, __HIP_MEMORY_SCOPE_AGENT);
        }
        return;
    }

    // ---------- router for batch b ----------
    const int b = blockIdx.x - POOL_BLOCKS;

    __shared__ float fused[FAN];
    __shared__ float logits_s[E_];
    __shared__ int   sel_s[K_];

    // task softmax first — independent of pooled, hides under the wait
    if (tid < 64) {
        float v1 = task_cls[b * NCLS + tid];
        bool has2 = (tid + 64) < NCLS;
        float v2 = has2 ? task_cls[b * NCLS + tid + 64] : -INFINITY;
        float m = fmaxf(v1, v2);
        #pragma unroll
        for (int off = 32; off > 0; off >>= 1) m = fmaxf(m, __shfl_down(m, off));
        m = __shfl(m, 0);
        float e1 = __expf(v1 - m);
        float e2 = has2 ? __expf(v2 - m) : 0.0f;
        float sm = e1 + e2;
        #pragma unroll
        for (int off = 32; off > 0; off >>= 1) sm += __shfl_down(sm, off);
        sm = __shfl(sm, 0);
        float inv = 1.0f / sm;
        fused[C_ + tid] = e1 * inv;
        if (has2) fused[C_ + tid + 64] = e2 * inv;
    }

    // wait for this batch's 768 pooled rows (relaxed polls — no cache maintenance)
    if (tid == 0) {
        while (__hip_atomic_load(&counters[b * CTR_STRIDE], __ATOMIC_RELAXED,
                                 __HIP_MEMORY_SCOPE_AGENT) < (unsigned)ROWS_PER_BATCH)
            __builtin_amdgcn_s_sleep(2);
    }
    __syncthreads();

    for (int i = tid; i < C_; i += 256)
        fused[i] = __hip_atomic_load(&pooled[b * C_ + i],
                                     __ATOMIC_RELAXED, __HIP_MEMORY_SCOPE_AGENT);
    __syncthreads();

    // 16 expert dot products: wave w handles experts 4w..4w+3
    #pragma unroll
    for (int q = 0; q < 4; ++q) {
        const int e = wav * 4 + q;
        const float* wr = Wm + (size_t)e * FAN;
        float acc = 0.0f;
        for (int j = lane; j < FAN; j += 64) acc += fused[j] * wr[j];
        #pragma unroll
        for (int off = 32; off > 0; off >>= 1) acc += __shfl_down(acc, off);
        if (lane == 0) {
            float lg = acc + bias[e];
            logits_s[e] = lg;
            out[b * E_ + e] = lg;                 // router_logits [B,E] @ 0
        }
    }
    __syncthreads();

    // top-2 (strict > keeps lowest index on ties, matching lax.top_k)
    if (tid == 0) {
        float m1 = -INFINITY, m2 = -INFINITY;
        int i1 = 0, i2 = 0;
        #pragma unroll
        for (int e = 0; e < E_; ++e) {
            float v = logits_s[e];
            if (v > m1) { m2 = m1; i2 = i1; m1 = v; i1 = e; }
            else if (v > m2) { m2 = v; i2 = e; }
        }
        float r = expf(m2 - m1);
        float w0 = 1.0f / (1.0f + r);
        float w1 = r * w0;
        out[1024 + b * K_ + 0] = w0;              // router_weights [B,K] @ 1024
        out[1024 + b * K_ + 1] = w1;
        out[1152 + b * K_ + 0] = (float)i1;       // selected_experts [B,K] @ 1152
        out[1152 + b * K_ + 1] = (float)i2;
        sel_s[0] = i1; sel_s[1] = i2;
    }
    __syncthreads();

    // expert_mask [E,K,B] @ 1280 : flat e*K*B + k*B + b
    if (tid < E_ * K_) {
        int e = tid >> 1;
        int k = tid & 1;
        out[1280 + e * (K_ * B_) + k * B_ + b] = (sel_s[k] == e) ? 1.0f : 0.0f;
    }
}

extern "C" void kernel_launch(void* const* d_in, const int* in_sizes, int n_in,
                              void* d_out, int out_size, void* d_ws, size_t ws_size,
                              hipStream_t stream) {
    const float* hidden   = (const float*)d_in[0];  // [64,768,32,32]
    const float* task_cls = (const float*)d_in[1];  // [64,100]
    const float* Wm       = (const float*)d_in[2];  // [16,868]
    const float* bias     = (const float*)d_in[3];  // [16]
    float* out = (float*)d_out;

    unsigned int* counters = (unsigned int*)d_ws;      // 64 x 16 uints (line-padded)
    float* pooled = (float*)((char*)d_ws + B_ * CTR_STRIDE * sizeof(unsigned int));

    (void)hipMemsetAsync(counters, 0, B_ * CTR_STRIDE * sizeof(unsigned int), stream);
    fused_kernel<<<POOL_BLOCKS + B_, 256, 0, stream>>>(hidden, task_cls, Wm, bias,
                                                       out, pooled, counters);
}

// Round 9
// 53.516 us; speedup vs baseline: 11.4985x; 1.0335x over previous
//
#include <hip/hip_runtime.h>
#include <math.h>

#define B_   64
#define C_   768
#define HW_  1024          // 32*32
#define NCLS 100
#define E_   16
#define K_   2
#define FAN  (C_ + NCLS)   // 868

typedef float vfloat4 __attribute__((ext_vector_type(4)));

// Best measured configuration (R5): two kernels, plain cached loads, no
// cross-block sync. Pool: one wave per TWO (b,c) rows, 8 independent
// float4 loads/thread. Fusion variants (R3/R6/R7/R8) were all >= this;
// the kernel boundary is the cheapest producer->consumer sync on gfx950.
__global__ __launch_bounds__(256) void pool_kernel(const float* __restrict__ x,
                                                   float* __restrict__ pooled) {
    const int wave = (blockIdx.x * 256 + threadIdx.x) >> 6;   // 0..24575
    const int lane = threadIdx.x & 63;
    const int r0   = wave * 2;                                // first of 2 rows

    const vfloat4* p0 = reinterpret_cast<const vfloat4*>(x + (size_t)r0 * HW_);
    const vfloat4* p1 = reinterpret_cast<const vfloat4*>(x + (size_t)(r0 + 1) * HW_);
    vfloat4 a0 = p0[lane];
    vfloat4 a1 = p0[lane + 64];
    vfloat4 a2 = p0[lane + 128];
    vfloat4 a3 = p0[lane + 192];
    vfloat4 b0 = p1[lane];
    vfloat4 b1 = p1[lane + 64];
    vfloat4 b2 = p1[lane + 128];
    vfloat4 b3 = p1[lane + 192];

    float s0 = (a0.x + a0.y + a0.z + a0.w) + (a1.x + a1.y + a1.z + a1.w)
             + (a2.x + a2.y + a2.z + a2.w) + (a3.x + a3.y + a3.z + a3.w);
    float s1 = (b0.x + b0.y + b0.z + b0.w) + (b1.x + b1.y + b1.z + b1.w)
             + (b2.x + b2.y + b2.z + b2.w) + (b3.x + b3.y + b3.z + b3.w);

    #pragma unroll
    for (int off = 32; off > 0; off >>= 1) {
        s0 += __shfl_down(s0, off);
        s1 += __shfl_down(s1, off);
    }
    if (lane == 0) {
        pooled[r0]     = s0 * (1.0f / 1024.0f);
        pooled[r0 + 1] = s1 * (1.0f / 1024.0f);
    }
}

// One block per batch element. 256 threads = 4 waves.
__global__ __launch_bounds__(256) void router_kernel(const float* __restrict__ pooled,
                                                     const float* __restrict__ task_cls,
                                                     const float* __restrict__ Wm,
                                                     const float* __restrict__ bias,
                                                     float* __restrict__ out) {
    const int b    = blockIdx.x;
    const int tid  = threadIdx.x;
    const int lane = tid & 63;
    const int wav  = tid >> 6;

    __shared__ float fused[FAN];
    __shared__ float logits_s[E_];
    __shared__ int   sel_s[K_];

    for (int i = tid; i < C_; i += 256) fused[i] = pooled[b * C_ + i];

    // softmax(task_cls[b]) -> fused[768..867]; wave 0 handles all 100 elems
    if (tid < 64) {
        float v1 = task_cls[b * NCLS + tid];
        bool has2 = (tid + 64) < NCLS;
        float v2 = has2 ? task_cls[b * NCLS + tid + 64] : -INFINITY;
        float m = fmaxf(v1, v2);
        #pragma unroll
        for (int off = 32; off > 0; off >>= 1) m = fmaxf(m, __shfl_down(m, off));
        m = __shfl(m, 0);
        float e1 = __expf(v1 - m);
        float e2 = has2 ? __expf(v2 - m) : 0.0f;
        float sm = e1 + e2;
        #pragma unroll
        for (int off = 32; off > 0; off >>= 1) sm += __shfl_down(sm, off);
        sm = __shfl(sm, 0);
        float inv = 1.0f / sm;
        fused[C_ + tid] = e1 * inv;
        if (has2) fused[C_ + tid + 64] = e2 * inv;
    }
    __syncthreads();

    // 16 expert dot products: wave w handles experts 4w..4w+3
    #pragma unroll
    for (int q = 0; q < 4; ++q) {
        const int e = wav * 4 + q;
        const float* wr = Wm + (size_t)e * FAN;
        float acc = 0.0f;
        for (int j = lane; j < FAN; j += 64) acc += fused[j] * wr[j];
        #pragma unroll
        for (int off = 32; off > 0; off >>= 1) acc += __shfl_down(acc, off);
        if (lane == 0) {
            float lg = acc + bias[e];
            logits_s[e] = lg;
            out[b * E_ + e] = lg;                 // router_logits [B,E] @ 0
        }
    }
    __syncthreads();

    // top-2 (strict > keeps lowest index on ties, matching lax.top_k)
    if (tid == 0) {
        float m1 = -INFINITY, m2 = -INFINITY;
        int i1 = 0, i2 = 0;
        #pragma unroll
        for (int e = 0; e < E_; ++e) {
            float v = logits_s[e];
            if (v > m1) { m2 = m1; i2 = i1; m1 = v; i1 = e; }
            else if (v > m2) { m2 = v; i2 = e; }
        }
        float r = expf(m2 - m1);
        float w0 = 1.0f / (1.0f + r);
        float w1 = r * w0;
        out[1024 + b * K_ + 0] = w0;              // router_weights [B,K] @ 1024
        out[1024 + b * K_ + 1] = w1;
        out[1152 + b * K_ + 0] = (float)i1;       // selected_experts [B,K] @ 1152
        out[1152 + b * K_ + 1] = (float)i2;
        sel_s[0] = i1; sel_s[1] = i2;
    }
    __syncthreads();

    // expert_mask [E,K,B] @ 1280 : flat e*K*B + k*B + b
    if (tid < E_ * K_) {
        int e = tid >> 1;
        int k = tid & 1;
        out[1280 + e * (K_ * B_) + k * B_ + b] = (sel_s[k] == e) ? 1.0f : 0.0f;
    }
}

extern "C" void kernel_launch(void* const* d_in, const int* in_sizes, int n_in,
                              void* d_out, int out_size, void* d_ws, size_t ws_size,
                              hipStream_t stream) {
    const float* hidden   = (const float*)d_in[0];  // [64,768,32,32]
    const float* task_cls = (const float*)d_in[1];  // [64,100]
    const float* Wm       = (const float*)d_in[2];  // [16,868]
    const float* bias     = (const float*)d_in[3];  // [16]
    float* out = (float*)d_out;
    float* pooled = (float*)d_ws;                   // B*C floats = 192 KiB

    // 49152 rows, 2 rows per wave, 4 waves per block -> 6144 blocks
    pool_kernel<<<6144, 256, 0, stream>>>(hidden, pooled);
    router_kernel<<<B_, 256, 0, stream>>>(pooled, task_cls, Wm, bias, out);
}

// Round 10
// 41.100 us; speedup vs baseline: 14.9721x; 1.3021x over previous
//
#include <hip/hip_runtime.h>
#include <math.h>

#define B_   64
#define C_   768
#define HW_  1024          // 32*32
#define NCLS 100
#define E_   16
#define K_   2
#define FAN  (C_ + NCLS)   // 868

typedef float vfloat4 __attribute__((ext_vector_type(4)));

// Pool: one wave per TWO (b,c) rows, 8 independent float4 loads/thread.
// (Plateau-verified: R1/R5/R8/R9 all 53.5-55.3 us; fusion variants lose.)
__global__ __launch_bounds__(256) void pool_kernel(const float* __restrict__ x,
                                                   float* __restrict__ pooled) {
    const int wave = (blockIdx.x * 256 + threadIdx.x) >> 6;   // 0..24575
    const int lane = threadIdx.x & 63;
    const int r0   = wave * 2;                                // first of 2 rows

    const vfloat4* p0 = reinterpret_cast<const vfloat4*>(x + (size_t)r0 * HW_);
    const vfloat4* p1 = reinterpret_cast<const vfloat4*>(x + (size_t)(r0 + 1) * HW_);
    vfloat4 a0 = p0[lane];
    vfloat4 a1 = p0[lane + 64];
    vfloat4 a2 = p0[lane + 128];
    vfloat4 a3 = p0[lane + 192];
    vfloat4 b0 = p1[lane];
    vfloat4 b1 = p1[lane + 64];
    vfloat4 b2 = p1[lane + 128];
    vfloat4 b3 = p1[lane + 192];

    float s0 = (a0.x + a0.y + a0.z + a0.w) + (a1.x + a1.y + a1.z + a1.w)
             + (a2.x + a2.y + a2.z + a2.w) + (a3.x + a3.y + a3.z + a3.w);
    float s1 = (b0.x + b0.y + b0.z + b0.w) + (b1.x + b1.y + b1.z + b1.w)
             + (b2.x + b2.y + b2.z + b2.w) + (b3.x + b3.y + b3.z + b3.w);

    #pragma unroll
    for (int off = 32; off > 0; off >>= 1) {
        s0 += __shfl_down(s0, off);
        s1 += __shfl_down(s1, off);
    }
    if (lane == 0) {
        pooled[r0]     = s0 * (1.0f / 1024.0f);
        pooled[r0 + 1] = s1 * (1.0f / 1024.0f);
    }
}

// Router: one block per batch. Each wave computes its 4 experts CONCURRENTLY
// (4 accumulators, one LDS read feeds 4 FMAs, 4 W-streams in flight) instead
// of 4 sequential latency-bound passes.
__global__ __launch_bounds__(256) void router_kernel(const float* __restrict__ pooled,
                                                     const float* __restrict__ task_cls,
                                                     const float* __restrict__ Wm,
                                                     const float* __restrict__ bias,
                                                     float* __restrict__ out) {
    const int b    = blockIdx.x;
    const int tid  = threadIdx.x;
    const int lane = tid & 63;
    const int wav  = tid >> 6;

    __shared__ float fused[FAN];
    __shared__ float logits_s[E_];
    __shared__ int   sel_s[K_];

    // pooled image features -> fused[0..767] (float4 staging, 192 vec loads)
    if (tid < 192) {
        reinterpret_cast<vfloat4*>(fused)[tid] =
            reinterpret_cast<const vfloat4*>(pooled + b * C_)[tid];
    }

    // softmax(task_cls[b]) -> fused[768..867]; wave 1 handles all 100 elems
    if (wav == 1) {
        float v1 = task_cls[b * NCLS + lane];
        bool has2 = (lane + 64) < NCLS;
        float v2 = has2 ? task_cls[b * NCLS + lane + 64] : -INFINITY;
        float m = fmaxf(v1, v2);
        #pragma unroll
        for (int off = 32; off > 0; off >>= 1) m = fmaxf(m, __shfl_down(m, off));
        m = __shfl(m, 0);
        float e1 = __expf(v1 - m);
        float e2 = has2 ? __expf(v2 - m) : 0.0f;
        float sm = e1 + e2;
        #pragma unroll
        for (int off = 32; off > 0; off >>= 1) sm += __shfl_down(sm, off);
        sm = __shfl(sm, 0);
        float inv = 1.0f / sm;
        fused[C_ + lane] = e1 * inv;
        if (has2) fused[C_ + lane + 64] = e2 * inv;
    }
    __syncthreads();

    // 16 expert dots: wave w owns experts 4w..4w+3, computed concurrently
    {
        const int e0 = wav * 4;
        const float* w0 = Wm + (size_t)(e0 + 0) * FAN;
        const float* w1 = Wm + (size_t)(e0 + 1) * FAN;
        const float* w2 = Wm + (size_t)(e0 + 2) * FAN;
        const float* w3 = Wm + (size_t)(e0 + 3) * FAN;
        float acc0 = 0.0f, acc1 = 0.0f, acc2 = 0.0f, acc3 = 0.0f;
        for (int j = lane; j < FAN; j += 64) {
            float f = fused[j];
            acc0 += f * w0[j];
            acc1 += f * w1[j];
            acc2 += f * w2[j];
            acc3 += f * w3[j];
        }
        #pragma unroll
        for (int off = 32; off > 0; off >>= 1) {
            acc0 += __shfl_down(acc0, off);
            acc1 += __shfl_down(acc1, off);
            acc2 += __shfl_down(acc2, off);
            acc3 += __shfl_down(acc3, off);
        }
        if (lane == 0) {
            float l0 = acc0 + bias[e0 + 0];
            float l1 = acc1 + bias[e0 + 1];
            float l2 = acc2 + bias[e0 + 2];
            float l3 = acc3 + bias[e0 + 3];
            logits_s[e0 + 0] = l0;  out[b * E_ + e0 + 0] = l0;  // router_logits @0
            logits_s[e0 + 1] = l1;  out[b * E_ + e0 + 1] = l1;
            logits_s[e0 + 2] = l2;  out[b * E_ + e0 + 2] = l2;
            logits_s[e0 + 3] = l3;  out[b * E_ + e0 + 3] = l3;
        }
    }
    __syncthreads();

    // top-2 (strict > keeps lowest index on ties, matching lax.top_k)
    if (tid == 0) {
        float m1 = -INFINITY, m2 = -INFINITY;
        int i1 = 0, i2 = 0;
        #pragma unroll
        for (int e = 0; e < E_; ++e) {
            float v = logits_s[e];
            if (v > m1) { m2 = m1; i2 = i1; m1 = v; i1 = e; }
            else if (v > m2) { m2 = v; i2 = e; }
        }
        float r = expf(m2 - m1);
        float w0 = 1.0f / (1.0f + r);
        float w1 = r * w0;
        out[1024 + b * K_ + 0] = w0;              // router_weights [B,K] @ 1024
        out[1024 + b * K_ + 1] = w1;
        out[1152 + b * K_ + 0] = (float)i1;       // selected_experts [B,K] @ 1152
        out[1152 + b * K_ + 1] = (float)i2;
        sel_s[0] = i1; sel_s[1] = i2;
    }
    __syncthreads();

    // expert_mask [E,K,B] @ 1280 : flat e*K*B + k*B + b
    if (tid < E_ * K_) {
        int e = tid >> 1;
        int k = tid & 1;
        out[1280 + e * (K_ * B_) + k * B_ + b] = (sel_s[k] == e) ? 1.0f : 0.0f;
    }
}

extern "C" void kernel_launch(void* const* d_in, const int* in_sizes, int n_in,
                              void* d_out, int out_size, void* d_ws, size_t ws_size,
                              hipStream_t stream) {
    const float* hidden   = (const float*)d_in[0];  // [64,768,32,32]
    const float* task_cls = (const float*)d_in[1];  // [64,100]
    const float* Wm       = (const float*)d_in[2];  // [16,868]
    const float* bias     = (const float*)d_in[3];  // [16]
    float* out = (float*)d_out;
    float* pooled = (float*)d_ws;                   // B*C floats = 192 KiB

    // 49152 rows, 2 rows per wave, 4 waves per block -> 6144 blocks
    pool_kernel<<<6144, 256, 0, stream>>>(hidden, pooled);
    router_kernel<<<B_, 256, 0, stream>>>(pooled, task_cls, Wm, bias, out);
}